// Round 2
// baseline (95.151 us; speedup 1.0000x reference)
//
#include <hip/hip_runtime.h>

// Output layout per row (B*N rows, 512 floats each):
//   out[row][i*128 + 2m + 0] = cos(th) + sin(th)
//   out[row][i*128 + 2m + 1] = cos(th) - sin(th)
// with th = 2*pi * x[row][i] * 10000^(-m/64), i in [0,4), m in [0,64).
//
// v_sin_f32 / v_cos_f32 take REVOLUTIONS: sin(2*pi*r). So r = x * 10000^(-m/64)
// directly — no 2*pi multiply, no range reduction (r in [0,1)).

typedef float vf4 __attribute__((ext_vector_type(4)));

__global__ __launch_bounds__(256) void rope_enc_kernel(
    const float* __restrict__ x, float* __restrict__ out, int nrows) {
  int tid  = blockIdx.x * blockDim.x + threadIdx.x;
  int row  = tid >> 5;          // 32 threads per row
  if (row >= nrows) return;
  int lane = tid & 31;          // owns m = 2*lane, 2*lane+1

  vf4 xr = *reinterpret_cast<const vf4*>(x + (size_t)row * 4);
  float xc[4] = {xr.x, xr.y, xr.z, xr.w};

  const float C    = 0.20762050593045952f;   // log2(10000)/64
  const float STEP = 0.86596432336006540f;   // 10000^(-1/64)
  float f0 = __builtin_amdgcn_exp2f(-(float)(lane * 2) * C);  // 10000^(-2*lane/64)
  float f1 = f0 * STEP;

  // d = i*128 + 2*m, m = 2*lane  ->  i*128 + 4*lane
  float* orow = out + (size_t)row * 512 + (size_t)(lane * 4);

#pragma unroll
  for (int i = 0; i < 4; ++i) {
    float r0 = xc[i] * f0;
    float r1 = xc[i] * f1;
    float s0 = __builtin_amdgcn_sinf(r0);
    float c0 = __builtin_amdgcn_cosf(r0);
    float s1 = __builtin_amdgcn_sinf(r1);
    float c1 = __builtin_amdgcn_cosf(r1);
    vf4 v;
    v.x = c0 + s0;
    v.y = c0 - s0;
    v.z = c1 + s1;
    v.w = c1 - s1;
    __builtin_nontemporal_store(v, reinterpret_cast<vf4*>(orow + i * 128));
  }
}

extern "C" void kernel_launch(void* const* d_in, const int* in_sizes, int n_in,
                              void* d_out, int out_size, void* d_ws, size_t ws_size,
                              hipStream_t stream) {
  const float* x = (const float*)d_in[0];
  float* out = (float*)d_out;
  int nrows = in_sizes[0] / 4;              // B*N = 262144
  int total_threads = nrows * 32;
  dim3 block(256);
  dim3 grid((total_threads + 255) / 256);
  rope_enc_kernel<<<grid, block, 0, stream>>>(x, out, nrows);
}